// Round 10
// baseline (302.880 us; speedup 1.0000x reference)
//
#include <hip/hip_runtime.h>
#include <hip/hip_bf16.h>
#include <math.h>

typedef __bf16 bf16x8 __attribute__((ext_vector_type(8)));
typedef __bf16 bf16x4 __attribute__((ext_vector_type(4)));
typedef float  f32x4  __attribute__((ext_vector_type(4)));

#define LH 264   // Hs row stride in bf16 elems (528 B); 132 dwords == 4 mod 32

// Feature permutation for layers 0/1 Wt packing: swap bits [3:2] <-> [5:4].
__device__ __host__ inline int fperm(int p) {
  return (p & 0xC0) | ((p & 0x0C) << 2) | ((p >> 2) & 0x0C) | (p & 3);
}

// ---------------- K1: conv0 (512 blk) | wt_frag (24 blk) | hq + sbuf zero (64 blk) -----------
__global__ __launch_bounds__(256) void k1(const float* __restrict__ img, const float* __restrict__ w0,
    const float* __restrict__ bs0, const float* __restrict__ bb0,
    const float* __restrict__ g2, const float* __restrict__ g3, const float* __restrict__ g4,
    const float* __restrict__ gw1, const float* __restrict__ gb1, const float* __restrict__ qst,
    float* __restrict__ c0, __bf16* __restrict__ Wt, float* __restrict__ hq,
    float* __restrict__ sbuf) {
  __shared__ __align__(16) float smem[8224];   // wt tile [32][257] is the max user
  const int blk = blockIdx.x, t = threadIdx.x;

  if (blk < 512) {
    // ---- conv0: 3->24, 128x128 -> 64x64, 2 pos/thread ----
    float* wl = smem;                          // 648
    for (int i = t; i < 648; i += 256) wl[i] = w0[i];
    __syncthreads();
    const int H = 128, W = 128, OH = 64, OW = 64;
    int idx = blk * 256 + t;
    int oxh = idx & 31; int tt = idx >> 5; int oy = tt & 63; int n = tt >> 6;
    int ox0 = oxh * 2;
    float acc0[24], acc1[24];
#pragma unroll
    for (int co = 0; co < 24; ++co) { acc0[co] = 0.f; acc1[co] = 0.f; }
    for (int ci = 0; ci < 3; ++ci) {
      const float* xp = img + (size_t)(n * 3 + ci) * H * W;
#pragma unroll
      for (int ky = 0; ky < 3; ++ky) {
        int iy = 2 * oy + ky - 1;
        if (iy < 0 || iy >= H) continue;
        const float* row = xp + (size_t)iy * W;
        int ixb = 2 * ox0 - 1;
        float in[7];
#pragma unroll
        for (int u = 0; u < 7; ++u) {
          int ix = ixb + u;
          in[u] = (ix >= 0 && ix < W) ? row[ix] : 0.f;
        }
#pragma unroll
        for (int kx = 0; kx < 3; ++kx) {
          const float* wp = &wl[((ky * 3 + kx) * 3 + ci) * 24];
          float v0 = in[kx], v1 = in[kx + 2];
#pragma unroll
          for (int co = 0; co < 24; ++co) {
            float wv = wp[co];
            acc0[co] += v0 * wv;
            acc1[co] += v1 * wv;
          }
        }
      }
    }
    float* yp = c0 + (size_t)n * 24 * OH * OW + (size_t)oy * OW + ox0;
#pragma unroll
    for (int co = 0; co < 24; ++co) {
      float s = bs0[co], b = bb0[co];
      yp[(size_t)co * OH * OW]     = fmaxf(acc0[co] * s + b, 0.f);
      yp[(size_t)co * OH * OW + 1] = fmaxf(acc1[co] * s + b, 0.f);
    }
  } else if (blk < 536) {
    // ---- wt_frag: g_w2/3/4 (256x256 [k][n]) -> Wt bf16 MFMA fragment order ----
    float* tile = smem;                        // [32][257]
    const int lb = blk - 512;
    const int l = lb >> 3, ks = lb & 7;
    const float* src = (l == 0) ? g2 : (l == 1) ? g3 : g4;
    for (int kk = 0; kk < 32; ++kk) tile[kk * 257 + t] = src[(ks * 32 + kk) * 256 + t];
    __syncthreads();
    const int q = t & 3, nb = t >> 2;
    __bf16* out = Wt + (size_t)(l * 8 + ks) * 8192;
#pragma unroll
    for (int i = 0; i < 4; ++i) {
      int nn = i * 64 + nb;
      int fsel = (l < 2) ? fperm(nn) : nn;
      bf16x8 v;
#pragma unroll
      for (int j = 0; j < 8; ++j) v[j] = (__bf16)tile[(q * 8 + j) * 257 + fsel];
      *(bf16x8*)&out[nn * 32 + q * 8] = v;
    }
  } else {
    // ---- hq = qst @ W1c + g_b1 ; zero sbuf ----
    float* qs = smem;
    const int n = blk - 536;
    sbuf[n * 256 + t] = 0.f;
    if (t < 128) qs[t] = qst[n * 128 + t];
    __syncthreads();
    float a = gb1[t];
    for (int c = 0; c < 128; ++c) a += qs[c] * gw1[(52 + c) * 256 + t];
    hq[n * 256 + t] = a;
  }
}

// ---------------- K2: conv1 (24->24, 64x64 -> 32x32) — EXACT R2 form ------------------------
__global__ __launch_bounds__(256) void conv1_k(const float* __restrict__ x, const float* __restrict__ w,
                                               const float* __restrict__ sc, const float* __restrict__ bi,
                                               float* __restrict__ y) {
  const int H = 64, W = 64, OH = 32, OW = 32;
  __shared__ float wl[2592];
  const int half = blockIdx.x & 1, sb = blockIdx.x >> 1;
  for (int i = threadIdx.x; i < 2592; i += 256) {
    int co = i % 12, rest = i / 12;
    wl[i] = w[rest * 24 + half * 12 + co];
  }
  __syncthreads();

  int idx = sb * 256 + threadIdx.x;
  int oxh = idx & 15; int tt = idx >> 4; int oy = tt & 31; int n = tt >> 5;
  int ox0 = oxh * 2;

  float acc0[12], acc1[12];
#pragma unroll
  for (int co = 0; co < 12; ++co) { acc0[co] = 0.f; acc1[co] = 0.f; }

  for (int ci = 0; ci < 24; ++ci) {
    const float* xp = x + (size_t)(n * 24 + ci) * H * W;
#pragma unroll
    for (int ky = 0; ky < 3; ++ky) {
      int iy = 2 * oy + ky - 1;
      if (iy < 0 || iy >= H) continue;
      const float* row = xp + (size_t)iy * W;
      int ixb = 2 * ox0 - 1;
      float in[7];
#pragma unroll
      for (int u = 0; u < 7; ++u) {
        int ix = ixb + u;
        in[u] = (ix >= 0 && ix < W) ? row[ix] : 0.f;
      }
#pragma unroll
      for (int kx = 0; kx < 3; ++kx) {
        const float* wp = &wl[((ky * 3 + kx) * 24 + ci) * 12];
        float v0 = in[kx], v1 = in[kx + 2];
#pragma unroll
        for (int co = 0; co < 12; ++co) {
          float wv = wp[co];
          acc0[co] += v0 * wv;
          acc1[co] += v1 * wv;
        }
      }
    }
  }
  float* yp = y + (size_t)n * 24 * OH * OW + (size_t)(half * 12) * OH * OW + (size_t)oy * OW + ox0;
#pragma unroll
  for (int co = 0; co < 12; ++co) {
    int cog = half * 12 + co;
    float s = sc[cog], b = bi[cog];
    yp[(size_t)co * OH * OW]     = fmaxf(acc0[co] * s + b, 0.f);
    yp[(size_t)co * OH * OW + 1] = fmaxf(acc1[co] * s + b, 0.f);
  }
}

// ---------------- K3: chain2 split 2x (R7 form) + hq pre-add into hj -------------------------
// hj_out = hj + hq[n] so g_fused staging computes relu(hi + hj') with no hq load/add.
__global__ __launch_bounds__(256) void chain2_k(const float* __restrict__ c1,
    const float* __restrict__ w2, const float* __restrict__ bs2, const float* __restrict__ bb2,
    const float* __restrict__ w3, const float* __restrict__ bs3, const float* __restrict__ bb3,
    const float* __restrict__ gw1, const float* __restrict__ hqb,
    float* __restrict__ hi, float* __restrict__ hj) {
  __shared__ float sw[5184];
  __shared__ float s2l[24 * 144];   // [co][local pos] : up to 9 rows x 16
  __shared__ float s3l[24 * 32];    // [co][pos32]
  const int b = blockIdx.x, t = threadIdx.x;
  const int n = b >> 1, h = b & 1;
  const int row0 = (h == 0) ? 0 : 7;       // first s2 global row in this slab
  const int nrows = (h == 0) ? 8 : 9;

  for (int i = t; i < 5184; i += 256) sw[i] = w2[i];
  __syncthreads();
  if (t < nrows * 16) {  // conv2: one slab position, all 24 co
    int gr = row0 + (t >> 4);   // global oy2 in [0,16)
    int gx = t & 15;
    float acc[24];
#pragma unroll
    for (int co = 0; co < 24; ++co) acc[co] = 0.f;
    for (int ci = 0; ci < 24; ++ci) {
      const float* xp = c1 + (size_t)(n * 24 + ci) * 1024;  // 32x32
#pragma unroll
      for (int ky = 0; ky < 3; ++ky) {
        int iy = 2 * gr + ky - 1;
        if (iy < 0 || iy >= 32) continue;
#pragma unroll
        for (int kx = 0; kx < 3; ++kx) {
          int ix = 2 * gx + kx - 1;
          if (ix < 0 || ix >= 32) continue;
          float v = xp[iy * 32 + ix];
          const float* wp = &sw[((ky * 3 + kx) * 24 + ci) * 24];
#pragma unroll
          for (int co = 0; co < 24; ++co) acc[co] += v * wp[co];
        }
      }
    }
#pragma unroll
    for (int co = 0; co < 24; ++co)
      s2l[co * 144 + t] = fmaxf(acc[co] * bs2[co] + bb2[co], 0.f);
  }
  __syncthreads();
  for (int i = t; i < 5184; i += 256) sw[i] = w3[i];
  __syncthreads();
  {  // conv3: 32 pos (oy3 in [4h,4h+4)), cog = t>>5 covering 3 channels
    const int pos = t & 31, cog = t >> 5;
    const int oy3 = 4 * h + (pos >> 3), ox3 = pos & 7;
    float acc[3];
#pragma unroll
    for (int u = 0; u < 3; ++u) acc[u] = 0.f;
    for (int ci = 0; ci < 24; ++ci) {
      const float* cp = &s2l[ci * 144];
#pragma unroll
      for (int ky = 0; ky < 3; ++ky) {
        int gy2 = 2 * oy3 + ky - 1;
        if (gy2 < 0 || gy2 >= 16) continue;
        int ly = gy2 - row0;                 // in [0, nrows)
#pragma unroll
        for (int kx = 0; kx < 3; ++kx) {
          int ix = 2 * ox3 + kx - 1;
          if (ix < 0 || ix >= 16) continue;
          float v = cp[ly * 16 + ix];
          const float* wp = &sw[((ky * 3 + kx) * 24 + ci) * 24 + cog * 3];
#pragma unroll
          for (int u = 0; u < 3; ++u) acc[u] += v * wp[u];
        }
      }
    }
#pragma unroll
    for (int u = 0; u < 3; ++u) {
      int co = cog * 3 + u;
      s3l[co * 32 + pos] = fmaxf(acc[u] * bs3[co] + bb3[co], 0.f);
    }
  }
  // embed: thread t = output feature column; 32 p of this half
  float wa[26], wb[26];
#pragma unroll
  for (int c = 0; c < 26; ++c) {
    wa[c] = gw1[c * 256 + t];
    wb[c] = gw1[(26 + c) * 256 + t];
  }
  const float hqv = hqb[n * 256 + t];        // pre-add hq into hj stream
  __syncthreads();
  for (int pl = 0; pl < 32; ++pl) {
    int p = 32 * h + pl;                     // global p = oy3*8+ox3
    float a = 0.f, bv = 0.f;
#pragma unroll
    for (int c = 0; c < 24; ++c) {
      float v = s3l[c * 32 + pl];
      a += v * wa[c];
      bv += v * wb[c];
    }
    float cx = -1.f + (2.f / 7.f) * (float)(p & 7);
    float cy = -1.f + (2.f / 7.f) * (float)(p >> 3);
    a += cx * wa[24] + cy * wa[25];
    bv += cx * wb[24] + cy * wb[25];
    hi[(size_t)(n * 64 + p) * 256 + t] = a;
    hj[(size_t)(n * 64 + p) * 256 + t] = bv + hqv;
  }
}

// ---------------- K4: fused relation network (R7 structure + XCD swizzle, no hq) -------------
// XCD swizzle: 2048 blocks = 8 XCD x 256; cluster the 32 same-n blocks on one XCD so
// each XCD's L2 keeps that n's hj/hi resident (vs 8x replication under round-robin).
__global__ __launch_bounds__(256, 2)
void g_fused(const float* __restrict__ hi, const float* __restrict__ hj,
             const __bf16* __restrict__ Wt,
             const float* __restrict__ b2, const float* __restrict__ b3,
             const float* __restrict__ b4, float* __restrict__ s_out) {
  const int blk = ((blockIdx.x & 7) << 8) | (blockIdx.x >> 3);   // bijective (2048 % 8 == 0)
  const int n = blk >> 5, ib = blk & 31;
  const int tid = threadIdx.x;
  const int wave = tid >> 6, lane = tid & 63;
  const int q = lane >> 4, lr = lane & 15;

  __shared__ __align__(16) __bf16 Hs[128 * LH];

  const int half = lane >> 5, m = lane & 31;
  const int cb = m * 8;
  float4 hiA = *(const float4*)(hi + (size_t)(n * 64 + ib * 2 + half) * 256 + cb);
  float4 hiB = *(const float4*)(hi + (size_t)(n * 64 + ib * 2 + half) * 256 + cb + 4);
  float hh[8];
  hh[0] = hiA.x; hh[1] = hiA.y; hh[2] = hiA.z; hh[3] = hiA.w;
  hh[4] = hiB.x; hh[5] = hiB.y; hh[6] = hiB.z; hh[7] = hiB.w;

  float bias2[4];
#pragma unroll
  for (int c = 0; c < 4; ++c) bias2[c] = b4[wave * 64 + lr + c * 16];

  const float* hjb = hj + (size_t)n * 64 * 256;
#pragma unroll
  for (int it = 0; it < 16; ++it) {
    int j = it * 4 + wave;
    float4 va = *(const float4*)(hjb + j * 256 + cb);
    float4 vb = *(const float4*)(hjb + j * 256 + cb + 4);
    bf16x8 o;
    o[0] = (__bf16)fmaxf(va.x + hh[0], 0.f);
    o[1] = (__bf16)fmaxf(va.y + hh[1], 0.f);
    o[2] = (__bf16)fmaxf(va.z + hh[2], 0.f);
    o[3] = (__bf16)fmaxf(va.w + hh[3], 0.f);
    o[4] = (__bf16)fmaxf(vb.x + hh[4], 0.f);
    o[5] = (__bf16)fmaxf(vb.y + hh[5], 0.f);
    o[6] = (__bf16)fmaxf(vb.z + hh[6], 0.f);
    o[7] = (__bf16)fmaxf(vb.w + hh[7], 0.f);
    *(bf16x8*)&Hs[(size_t)(half * 64 + j) * LH + cb] = o;
  }
  __syncthreads();

  const __bf16* Bp = Wt + (size_t)wave * 2048 + lr * 32 + q * 8;
  const int colv = wave * 64 + q * 16;

  for (int l = 0; l < 2; ++l) {
    const __bf16* Bl = Bp + (size_t)l * 65536;
    const float* bb = (l == 0) ? b2 : b3;
    f32x4 bv[4];
#pragma unroll
    for (int c = 0; c < 4; ++c)
      bv[c] = *(const f32x4*)(bb + colv + c * 4);

    f32x4 acc[8][4];
#pragma unroll
    for (int r = 0; r < 8; ++r)
#pragma unroll
      for (int c = 0; c < 4; ++c) acc[r][c] = (f32x4){0.f, 0.f, 0.f, 0.f};

    bf16x8 bnxt[4];
#pragma unroll
    for (int c = 0; c < 4; ++c) bnxt[c] = *(const bf16x8*)&Bl[c * 512];
#pragma unroll
    for (int ks = 0; ks < 8; ++ks) {
      bf16x8 bcur[4];
#pragma unroll
      for (int c = 0; c < 4; ++c) bcur[c] = bnxt[c];
      if (ks < 7) {
#pragma unroll
        for (int c = 0; c < 4; ++c) bnxt[c] = *(const bf16x8*)&Bl[(ks + 1) * 8192 + c * 512];
      }
      bf16x8 a[8];
#pragma unroll
      for (int r = 0; r < 8; ++r)
        a[r] = *(const bf16x8*)&Hs[(size_t)(r * 16 + lr) * LH + ks * 32 + q * 8];
      __builtin_amdgcn_s_setprio(1);
#pragma unroll
      for (int r = 0; r < 8; ++r)
#pragma unroll
        for (int c = 0; c < 4; ++c)
          acc[r][c] = __builtin_amdgcn_mfma_f32_16x16x32_bf16(bcur[c], a[r], acc[r][c], 0, 0, 0);
      __builtin_amdgcn_s_setprio(0);
    }

    __syncthreads();
#pragma unroll
    for (int r = 0; r < 8; ++r) {
      bf16x8 oA, oB;
#pragma unroll
      for (int c = 0; c < 2; ++c)
#pragma unroll
        for (int reg = 0; reg < 4; ++reg)
          oA[c * 4 + reg] = (__bf16)fmaxf(acc[r][c][reg] + bv[c][reg], 0.f);
#pragma unroll
      for (int c = 2; c < 4; ++c)
#pragma unroll
        for (int reg = 0; reg < 4; ++reg)
          oB[(c - 2) * 4 + reg] = (__bf16)fmaxf(acc[r][c][reg] + bv[c][reg], 0.f);
      __bf16* wp = &Hs[(size_t)(r * 16 + lr) * LH + colv];
      *(bf16x8*)wp = oA;
      *(bf16x8*)(wp + 8) = oB;
    }
    __syncthreads();
  }

  {
    const __bf16* Bl = Bp + (size_t)2 * 65536;
    f32x4 acc[8][4];
#pragma unroll
    for (int r = 0; r < 8; ++r)
#pragma unroll
      for (int c = 0; c < 4; ++c) acc[r][c] = (f32x4){0.f, 0.f, 0.f, 0.f};

    bf16x8 bnxt[4];
#pragma unroll
    for (int c = 0; c < 4; ++c) bnxt[c] = *(const bf16x8*)&Bl[c * 512];
#pragma unroll
    for (int ks = 0; ks < 8; ++ks) {
      bf16x8 bcur[4];
#pragma unroll
      for (int c = 0; c < 4; ++c) bcur[c] = bnxt[c];
      if (ks < 7) {
#pragma unroll
        for (int c = 0; c < 4; ++c) bnxt[c] = *(const bf16x8*)&Bl[(ks + 1) * 8192 + c * 512];
      }
      bf16x8 a[8];
#pragma unroll
      for (int r = 0; r < 8; ++r)
        a[r] = *(const bf16x8*)&Hs[(size_t)(r * 16 + lr) * LH + ks * 32 + q * 8];
      __builtin_amdgcn_s_setprio(1);
#pragma unroll
      for (int r = 0; r < 8; ++r)
#pragma unroll
        for (int c = 0; c < 4; ++c)
          acc[r][c] = __builtin_amdgcn_mfma_f32_16x16x32_bf16(a[r], bcur[c], acc[r][c], 0, 0, 0);
      __builtin_amdgcn_s_setprio(0);
    }

#pragma unroll
    for (int c = 0; c < 4; ++c) {
      float cs = 0.f;
#pragma unroll
      for (int r = 0; r < 8; ++r)
#pragma unroll
        for (int reg = 0; reg < 4; ++reg)
          cs += fmaxf(acc[r][c][reg] + bias2[c], 0.f);
      cs += __shfl_xor(cs, 16);
      cs += __shfl_xor(cs, 32);
      if (q == 0) atomicAdd(&s_out[n * 256 + wave * 64 + lr + c * 16], cs);
    }
  }
}

// ---------------- K5: f-network + classifier + log_softmax (4-way ILP dot products) ----------
__global__ void f_net(const float* __restrict__ s, const float* __restrict__ fw1,
                      const float* __restrict__ fb1, const float* __restrict__ fw2,
                      const float* __restrict__ fb2, const float* __restrict__ cw,
                      const float* __restrict__ cb, float* __restrict__ out) {
  int n = blockIdx.x, t = threadIdx.x;
  __shared__ float buf[256], buf2[256], zs[32];
  buf[t] = s[n * 256 + t];
  __syncthreads();
  float a0 = 0.f, a1 = 0.f, a2 = 0.f, a3 = 0.f;
  for (int c = 0; c < 256; c += 4) {
    a0 += buf[c]     * fw1[c * 256 + t];
    a1 += buf[c + 1] * fw1[(c + 1) * 256 + t];
    a2 += buf[c + 2] * fw1[(c + 2) * 256 + t];
    a3 += buf[c + 3] * fw1[(c + 3) * 256 + t];
  }
  float a = fmaxf(fb1[t] + ((a0 + a1) + (a2 + a3)), 0.f);
  buf2[t] = a;
  __syncthreads();
  float y0 = 0.f, y1 = 0.f, y2 = 0.f, y3 = 0.f;
  for (int c = 0; c < 256; c += 4) {
    y0 += buf2[c]     * fw2[c * 256 + t];
    y1 += buf2[c + 1] * fw2[(c + 1) * 256 + t];
    y2 += buf2[c + 2] * fw2[(c + 2) * 256 + t];
    y3 += buf2[c + 3] * fw2[(c + 3) * 256 + t];
  }
  float y = fmaxf(fb2[t] + ((y0 + y1) + (y2 + y3)), 0.f);
  __syncthreads();
  buf[t] = y;
  __syncthreads();
  float z = 0.f;
  if (t < 32) {
    float z0 = 0.f, z1 = 0.f, z2 = 0.f, z3 = 0.f;
    for (int c = 0; c < 256; c += 4) {
      z0 += buf[c]     * cw[c * 32 + t];
      z1 += buf[c + 1] * cw[(c + 1) * 32 + t];
      z2 += buf[c + 2] * cw[(c + 2) * 32 + t];
      z3 += buf[c + 3] * cw[(c + 3) * 32 + t];
    }
    z = cb[t] + ((z0 + z1) + (z2 + z3));
    zs[t] = z;
  }
  __syncthreads();
  if (t < 32) {
    float mx = -1e30f;
    for (int c = 0; c < 32; ++c) mx = fmaxf(mx, zs[c]);
    float se = 0.f;
    for (int c = 0; c < 32; ++c) se += expf(zs[c] - mx);
    out[n * 32 + t] = z - mx - logf(se);
  }
}

extern "C" void kernel_launch(void* const* d_in, const int* in_sizes, int n_in,
                              void* d_out, int out_size, void* d_ws, size_t ws_size,
                              hipStream_t stream) {
  const float* img  = (const float*)d_in[0];
  const float* qst  = (const float*)d_in[1];
  const float* w0   = (const float*)d_in[2];
  const float* w1   = (const float*)d_in[3];
  const float* w2   = (const float*)d_in[4];
  const float* w3   = (const float*)d_in[5];
  const float* bs0  = (const float*)d_in[6];
  const float* bb0  = (const float*)d_in[7];
  const float* bs1  = (const float*)d_in[8];
  const float* bb1  = (const float*)d_in[9];
  const float* bs2  = (const float*)d_in[10];
  const float* bb2  = (const float*)d_in[11];
  const float* bs3  = (const float*)d_in[12];
  const float* bb3  = (const float*)d_in[13];
  const float* gw1  = (const float*)d_in[14];
  const float* gb1  = (const float*)d_in[15];
  const float* gw2  = (const float*)d_in[16];
  const float* gb2  = (const float*)d_in[17];
  const float* gw3  = (const float*)d_in[18];
  const float* gb3  = (const float*)d_in[19];
  const float* gw4  = (const float*)d_in[20];
  const float* gb4  = (const float*)d_in[21];
  const float* fw1  = (const float*)d_in[22];
  const float* fb1  = (const float*)d_in[23];
  const float* fw2  = (const float*)d_in[24];
  const float* fb2  = (const float*)d_in[25];
  const float* cw   = (const float*)d_in[26];
  const float* cb   = (const float*)d_in[27];

  char* ws = (char*)d_ws;
  float* c0 = (float*)(ws + 0);                    // 25,165,824 B NCHW (dead after conv1)
  float* c1 = (float*)(ws + 25165824);             //  6,291,456 B NCHW -> 31,457,280
  __bf16* Wt  = (__bf16*)(ws + 31457280);          //   393,216 B -> 31,850,496
  float*  hqb = (float*)(ws + 31850496);           //    65,536 B -> 31,916,032
  float*  sbuf = (float*)(ws + 31916032);          //    65,536 B -> 31,981,568
  float*  hi  = (float*)(ws + 0);                  // 4,194,304 B (dead-c0, written by chain2)
  float*  hj  = (float*)(ws + 4194304);            // 4,194,304 B (dead-c0; includes +hq)

  k1<<<600, 256, 0, stream>>>(img, w0, bs0, bb0, gw2, gw3, gw4, gw1, gb1, qst,
                              c0, Wt, hqb, sbuf);
  conv1_k<<<256, 256, 0, stream>>>(c0, w1, bs1, bb1, c1);
  chain2_k<<<128, 256, 0, stream>>>(c1, w2, bs2, bb2, w3, bs3, bb3, gw1, hqb, hi, hj);
  g_fused<<<2048, 256, 0, stream>>>(hi, hj, Wt, gb2, gb3, gb4, sbuf);
  f_net<<<64, 256, 0, stream>>>(sbuf, fw1, fb1, fw2, fb2, cw, cb, (float*)d_out);
}

// Round 11
// 298.599 us; speedup vs baseline: 1.0143x; 1.0143x over previous
//
#include <hip/hip_runtime.h>
#include <hip/hip_bf16.h>
#include <math.h>

typedef __bf16 bf16x8 __attribute__((ext_vector_type(8)));
typedef __bf16 bf16x4 __attribute__((ext_vector_type(4)));
typedef float  f32x4  __attribute__((ext_vector_type(4)));

#define LH 264   // Hs row stride in bf16 elems (528 B); 132 dwords == 4 mod 32

// Feature permutation for layers 0/1 Wt packing: swap bits [3:2] <-> [5:4].
__device__ __host__ inline int fperm(int p) {
  return (p & 0xC0) | ((p & 0x0C) << 2) | ((p >> 2) & 0x0C) | (p & 3);
}

// ---------------- K1: conv0 (512 blk) | wt_frag (24 blk) | hq + sbuf zero (64 blk) -----------
__global__ __launch_bounds__(256) void k1(const float* __restrict__ img, const float* __restrict__ w0,
    const float* __restrict__ bs0, const float* __restrict__ bb0,
    const float* __restrict__ g2, const float* __restrict__ g3, const float* __restrict__ g4,
    const float* __restrict__ gw1, const float* __restrict__ gb1, const float* __restrict__ qst,
    float* __restrict__ c0, __bf16* __restrict__ Wt, float* __restrict__ hq,
    float* __restrict__ sbuf) {
  __shared__ __align__(16) float smem[8224];   // wt tile [32][257] is the max user
  const int blk = blockIdx.x, t = threadIdx.x;

  if (blk < 512) {
    // ---- conv0: 3->24, 128x128 -> 64x64, 2 pos/thread ----
    float* wl = smem;                          // 648
    for (int i = t; i < 648; i += 256) wl[i] = w0[i];
    __syncthreads();
    const int H = 128, W = 128, OH = 64, OW = 64;
    int idx = blk * 256 + t;
    int oxh = idx & 31; int tt = idx >> 5; int oy = tt & 63; int n = tt >> 6;
    int ox0 = oxh * 2;
    float acc0[24], acc1[24];
#pragma unroll
    for (int co = 0; co < 24; ++co) { acc0[co] = 0.f; acc1[co] = 0.f; }
    for (int ci = 0; ci < 3; ++ci) {
      const float* xp = img + (size_t)(n * 3 + ci) * H * W;
#pragma unroll
      for (int ky = 0; ky < 3; ++ky) {
        int iy = 2 * oy + ky - 1;
        if (iy < 0 || iy >= H) continue;
        const float* row = xp + (size_t)iy * W;
        int ixb = 2 * ox0 - 1;
        float in[7];
#pragma unroll
        for (int u = 0; u < 7; ++u) {
          int ix = ixb + u;
          in[u] = (ix >= 0 && ix < W) ? row[ix] : 0.f;
        }
#pragma unroll
        for (int kx = 0; kx < 3; ++kx) {
          const float* wp = &wl[((ky * 3 + kx) * 3 + ci) * 24];
          float v0 = in[kx], v1 = in[kx + 2];
#pragma unroll
          for (int co = 0; co < 24; ++co) {
            float wv = wp[co];
            acc0[co] += v0 * wv;
            acc1[co] += v1 * wv;
          }
        }
      }
    }
    float* yp = c0 + (size_t)n * 24 * OH * OW + (size_t)oy * OW + ox0;
#pragma unroll
    for (int co = 0; co < 24; ++co) {
      float s = bs0[co], b = bb0[co];
      yp[(size_t)co * OH * OW]     = fmaxf(acc0[co] * s + b, 0.f);
      yp[(size_t)co * OH * OW + 1] = fmaxf(acc1[co] * s + b, 0.f);
    }
  } else if (blk < 536) {
    // ---- wt_frag: g_w2/3/4 (256x256 [k][n]) -> Wt bf16 MFMA fragment order ----
    float* tile = smem;                        // [32][257]
    const int lb = blk - 512;
    const int l = lb >> 3, ks = lb & 7;
    const float* src = (l == 0) ? g2 : (l == 1) ? g3 : g4;
    for (int kk = 0; kk < 32; ++kk) tile[kk * 257 + t] = src[(ks * 32 + kk) * 256 + t];
    __syncthreads();
    const int q = t & 3, nb = t >> 2;
    __bf16* out = Wt + (size_t)(l * 8 + ks) * 8192;
#pragma unroll
    for (int i = 0; i < 4; ++i) {
      int nn = i * 64 + nb;
      int fsel = (l < 2) ? fperm(nn) : nn;
      bf16x8 v;
#pragma unroll
      for (int j = 0; j < 8; ++j) v[j] = (__bf16)tile[(q * 8 + j) * 257 + fsel];
      *(bf16x8*)&out[nn * 32 + q * 8] = v;
    }
  } else {
    // ---- hq = qst @ W1c + g_b1 ; zero sbuf ----
    float* qs = smem;
    const int n = blk - 536;
    sbuf[n * 256 + t] = 0.f;
    if (t < 128) qs[t] = qst[n * 128 + t];
    __syncthreads();
    float a = gb1[t];
    for (int c = 0; c < 128; ++c) a += qs[c] * gw1[(52 + c) * 256 + t];
    hq[n * 256 + t] = a;
  }
}

// ---------------- K2: conv1 (24->24, 64x64 -> 32x32) — EXACT R2 form ------------------------
__global__ __launch_bounds__(256) void conv1_k(const float* __restrict__ x, const float* __restrict__ w,
                                               const float* __restrict__ sc, const float* __restrict__ bi,
                                               float* __restrict__ y) {
  const int H = 64, W = 64, OH = 32, OW = 32;
  __shared__ float wl[2592];
  const int half = blockIdx.x & 1, sb = blockIdx.x >> 1;
  for (int i = threadIdx.x; i < 2592; i += 256) {
    int co = i % 12, rest = i / 12;
    wl[i] = w[rest * 24 + half * 12 + co];
  }
  __syncthreads();

  int idx = sb * 256 + threadIdx.x;
  int oxh = idx & 15; int tt = idx >> 4; int oy = tt & 31; int n = tt >> 5;
  int ox0 = oxh * 2;

  float acc0[12], acc1[12];
#pragma unroll
  for (int co = 0; co < 12; ++co) { acc0[co] = 0.f; acc1[co] = 0.f; }

  for (int ci = 0; ci < 24; ++ci) {
    const float* xp = x + (size_t)(n * 24 + ci) * H * W;
#pragma unroll
    for (int ky = 0; ky < 3; ++ky) {
      int iy = 2 * oy + ky - 1;
      if (iy < 0 || iy >= H) continue;
      const float* row = xp + (size_t)iy * W;
      int ixb = 2 * ox0 - 1;
      float in[7];
#pragma unroll
      for (int u = 0; u < 7; ++u) {
        int ix = ixb + u;
        in[u] = (ix >= 0 && ix < W) ? row[ix] : 0.f;
      }
#pragma unroll
      for (int kx = 0; kx < 3; ++kx) {
        const float* wp = &wl[((ky * 3 + kx) * 24 + ci) * 12];
        float v0 = in[kx], v1 = in[kx + 2];
#pragma unroll
        for (int co = 0; co < 12; ++co) {
          float wv = wp[co];
          acc0[co] += v0 * wv;
          acc1[co] += v1 * wv;
        }
      }
    }
  }
  float* yp = y + (size_t)n * 24 * OH * OW + (size_t)(half * 12) * OH * OW + (size_t)oy * OW + ox0;
#pragma unroll
  for (int co = 0; co < 12; ++co) {
    int cog = half * 12 + co;
    float s = sc[cog], b = bi[cog];
    yp[(size_t)co * OH * OW]     = fmaxf(acc0[co] * s + b, 0.f);
    yp[(size_t)co * OH * OW + 1] = fmaxf(acc1[co] * s + b, 0.f);
  }
}

// ---------------- K3: chain2 split 2x: block = (n, oy-half) -> 128 blocks (R7/R9 form) -------
__global__ __launch_bounds__(256) void chain2_k(const float* __restrict__ c1,
    const float* __restrict__ w2, const float* __restrict__ bs2, const float* __restrict__ bb2,
    const float* __restrict__ w3, const float* __restrict__ bs3, const float* __restrict__ bb3,
    const float* __restrict__ gw1, float* __restrict__ hi, float* __restrict__ hj) {
  __shared__ float sw[5184];
  __shared__ float s2l[24 * 144];   // [co][local pos] : up to 9 rows x 16
  __shared__ float s3l[24 * 32];    // [co][pos32]
  const int b = blockIdx.x, t = threadIdx.x;
  const int n = b >> 1, h = b & 1;
  const int row0 = (h == 0) ? 0 : 7;       // first s2 global row in this slab
  const int nrows = (h == 0) ? 8 : 9;

  for (int i = t; i < 5184; i += 256) sw[i] = w2[i];
  __syncthreads();
  if (t < nrows * 16) {  // conv2: one slab position, all 24 co
    int gr = row0 + (t >> 4);   // global oy2 in [0,16)
    int gx = t & 15;
    float acc[24];
#pragma unroll
    for (int co = 0; co < 24; ++co) acc[co] = 0.f;
    for (int ci = 0; ci < 24; ++ci) {
      const float* xp = c1 + (size_t)(n * 24 + ci) * 1024;  // 32x32
#pragma unroll
      for (int ky = 0; ky < 3; ++ky) {
        int iy = 2 * gr + ky - 1;
        if (iy < 0 || iy >= 32) continue;
#pragma unroll
        for (int kx = 0; kx < 3; ++kx) {
          int ix = 2 * gx + kx - 1;
          if (ix < 0 || ix >= 32) continue;
          float v = xp[iy * 32 + ix];
          const float* wp = &sw[((ky * 3 + kx) * 24 + ci) * 24];
#pragma unroll
          for (int co = 0; co < 24; ++co) acc[co] += v * wp[co];
        }
      }
    }
#pragma unroll
    for (int co = 0; co < 24; ++co)
      s2l[co * 144 + t] = fmaxf(acc[co] * bs2[co] + bb2[co], 0.f);
  }
  __syncthreads();
  for (int i = t; i < 5184; i += 256) sw[i] = w3[i];
  __syncthreads();
  {  // conv3: 32 pos (oy3 in [4h,4h+4)), cog = t>>5 covering 3 channels
    const int pos = t & 31, cog = t >> 5;
    const int oy3 = 4 * h + (pos >> 3), ox3 = pos & 7;
    float acc[3];
#pragma unroll
    for (int u = 0; u < 3; ++u) acc[u] = 0.f;
    for (int ci = 0; ci < 24; ++ci) {
      const float* cp = &s2l[ci * 144];
#pragma unroll
      for (int ky = 0; ky < 3; ++ky) {
        int gy2 = 2 * oy3 + ky - 1;
        if (gy2 < 0 || gy2 >= 16) continue;
        int ly = gy2 - row0;                 // in [0, nrows)
#pragma unroll
        for (int kx = 0; kx < 3; ++kx) {
          int ix = 2 * ox3 + kx - 1;
          if (ix < 0 || ix >= 16) continue;
          float v = cp[ly * 16 + ix];
          const float* wp = &sw[((ky * 3 + kx) * 24 + ci) * 24 + cog * 3];
#pragma unroll
          for (int u = 0; u < 3; ++u) acc[u] += v * wp[u];
        }
      }
    }
#pragma unroll
    for (int u = 0; u < 3; ++u) {
      int co = cog * 3 + u;
      s3l[co * 32 + pos] = fmaxf(acc[u] * bs3[co] + bb3[co], 0.f);
    }
  }
  // embed: thread t = output feature column; 32 p of this half
  float wa[26], wb[26];
#pragma unroll
  for (int c = 0; c < 26; ++c) {
    wa[c] = gw1[c * 256 + t];
    wb[c] = gw1[(26 + c) * 256 + t];
  }
  __syncthreads();
  for (int pl = 0; pl < 32; ++pl) {
    int p = 32 * h + pl;                     // global p = oy3*8+ox3
    float a = 0.f, bv = 0.f;
#pragma unroll
    for (int c = 0; c < 24; ++c) {
      float v = s3l[c * 32 + pl];
      a += v * wa[c];
      bv += v * wb[c];
    }
    float cx = -1.f + (2.f / 7.f) * (float)(p & 7);
    float cy = -1.f + (2.f / 7.f) * (float)(p >> 3);
    a += cx * wa[24] + cy * wa[25];
    bv += cx * wb[24] + cy * wb[25];
    hi[(size_t)(n * 64 + p) * 256 + t] = a;
    hj[(size_t)(n * 64 + p) * 256 + t] = bv;
  }
}

// ---------------- K4: fused relation network (R9 form + XCD swizzle only) --------------------
// XCD swizzle (bijective, 2048 % 8 == 0): clusters the 32 same-n blocks on one XCD so
// each XCD's L2 keeps that n's hj/hi resident. R10 verified: FETCH 20.3 -> 5.8 MB,
// g_fused 93.1 -> 90.5 us. hq handling stays in-staging (R9 form; the R10 hq-preadd
// bundle showed a +6 us residual regression and is stripped).
__global__ __launch_bounds__(256, 2)
void g_fused(const float* __restrict__ hi, const float* __restrict__ hj,
             const float* __restrict__ hq, const __bf16* __restrict__ Wt,
             const float* __restrict__ b2, const float* __restrict__ b3,
             const float* __restrict__ b4, float* __restrict__ s_out) {
  const int blk = ((blockIdx.x & 7) << 8) | (blockIdx.x >> 3);   // XCD swizzle
  const int n = blk >> 5, ib = blk & 31;
  const int tid = threadIdx.x;
  const int wave = tid >> 6, lane = tid & 63;
  const int q = lane >> 4, lr = lane & 15;

  __shared__ __align__(16) __bf16 Hs[128 * LH];

  const int half = lane >> 5, m = lane & 31;
  const int cb = m * 8;
  float4 hqA = *(const float4*)(hq + (size_t)n * 256 + cb);
  float4 hqB = *(const float4*)(hq + (size_t)n * 256 + cb + 4);
  float4 hiA = *(const float4*)(hi + (size_t)(n * 64 + ib * 2 + half) * 256 + cb);
  float4 hiB = *(const float4*)(hi + (size_t)(n * 64 + ib * 2 + half) * 256 + cb + 4);
  float hh[8];
  hh[0] = hiA.x + hqA.x; hh[1] = hiA.y + hqA.y; hh[2] = hiA.z + hqA.z; hh[3] = hiA.w + hqA.w;
  hh[4] = hiB.x + hqB.x; hh[5] = hiB.y + hqB.y; hh[6] = hiB.z + hqB.z; hh[7] = hiB.w + hqB.w;

  float bias2[4];
#pragma unroll
  for (int c = 0; c < 4; ++c) bias2[c] = b4[wave * 64 + lr + c * 16];

  const float* hjb = hj + (size_t)n * 64 * 256;
#pragma unroll
  for (int it = 0; it < 16; ++it) {
    int j = it * 4 + wave;
    float4 va = *(const float4*)(hjb + j * 256 + cb);
    float4 vb = *(const float4*)(hjb + j * 256 + cb + 4);
    bf16x8 o;
    o[0] = (__bf16)fmaxf(va.x + hh[0], 0.f);
    o[1] = (__bf16)fmaxf(va.y + hh[1], 0.f);
    o[2] = (__bf16)fmaxf(va.z + hh[2], 0.f);
    o[3] = (__bf16)fmaxf(va.w + hh[3], 0.f);
    o[4] = (__bf16)fmaxf(vb.x + hh[4], 0.f);
    o[5] = (__bf16)fmaxf(vb.y + hh[5], 0.f);
    o[6] = (__bf16)fmaxf(vb.z + hh[6], 0.f);
    o[7] = (__bf16)fmaxf(vb.w + hh[7], 0.f);
    *(bf16x8*)&Hs[(size_t)(half * 64 + j) * LH + cb] = o;
  }
  __syncthreads();

  const __bf16* Bp = Wt + (size_t)wave * 2048 + lr * 32 + q * 8;
  const int colv = wave * 64 + q * 16;

  for (int l = 0; l < 2; ++l) {
    const __bf16* Bl = Bp + (size_t)l * 65536;
    const float* bb = (l == 0) ? b2 : b3;
    f32x4 bv[4];
#pragma unroll
    for (int c = 0; c < 4; ++c)
      bv[c] = *(const f32x4*)(bb + colv + c * 4);

    f32x4 acc[8][4];
#pragma unroll
    for (int r = 0; r < 8; ++r)
#pragma unroll
      for (int c = 0; c < 4; ++c) acc[r][c] = (f32x4){0.f, 0.f, 0.f, 0.f};

    bf16x8 bnxt[4];
#pragma unroll
    for (int c = 0; c < 4; ++c) bnxt[c] = *(const bf16x8*)&Bl[c * 512];
#pragma unroll
    for (int ks = 0; ks < 8; ++ks) {
      bf16x8 bcur[4];
#pragma unroll
      for (int c = 0; c < 4; ++c) bcur[c] = bnxt[c];
      if (ks < 7) {
#pragma unroll
        for (int c = 0; c < 4; ++c) bnxt[c] = *(const bf16x8*)&Bl[(ks + 1) * 8192 + c * 512];
      }
      bf16x8 a[8];
#pragma unroll
      for (int r = 0; r < 8; ++r)
        a[r] = *(const bf16x8*)&Hs[(size_t)(r * 16 + lr) * LH + ks * 32 + q * 8];
      __builtin_amdgcn_s_setprio(1);
#pragma unroll
      for (int r = 0; r < 8; ++r)
#pragma unroll
        for (int c = 0; c < 4; ++c)
          acc[r][c] = __builtin_amdgcn_mfma_f32_16x16x32_bf16(bcur[c], a[r], acc[r][c], 0, 0, 0);
      __builtin_amdgcn_s_setprio(0);
    }

    __syncthreads();
#pragma unroll
    for (int r = 0; r < 8; ++r) {
      bf16x8 oA, oB;
#pragma unroll
      for (int c = 0; c < 2; ++c)
#pragma unroll
        for (int reg = 0; reg < 4; ++reg)
          oA[c * 4 + reg] = (__bf16)fmaxf(acc[r][c][reg] + bv[c][reg], 0.f);
#pragma unroll
      for (int c = 2; c < 4; ++c)
#pragma unroll
        for (int reg = 0; reg < 4; ++reg)
          oB[(c - 2) * 4 + reg] = (__bf16)fmaxf(acc[r][c][reg] + bv[c][reg], 0.f);
      __bf16* wp = &Hs[(size_t)(r * 16 + lr) * LH + colv];
      *(bf16x8*)wp = oA;
      *(bf16x8*)(wp + 8) = oB;
    }
    __syncthreads();
  }

  {
    const __bf16* Bl = Bp + (size_t)2 * 65536;
    f32x4 acc[8][4];
#pragma unroll
    for (int r = 0; r < 8; ++r)
#pragma unroll
      for (int c = 0; c < 4; ++c) acc[r][c] = (f32x4){0.f, 0.f, 0.f, 0.f};

    bf16x8 bnxt[4];
#pragma unroll
    for (int c = 0; c < 4; ++c) bnxt[c] = *(const bf16x8*)&Bl[c * 512];
#pragma unroll
    for (int ks = 0; ks < 8; ++ks) {
      bf16x8 bcur[4];
#pragma unroll
      for (int c = 0; c < 4; ++c) bcur[c] = bnxt[c];
      if (ks < 7) {
#pragma unroll
        for (int c = 0; c < 4; ++c) bnxt[c] = *(const bf16x8*)&Bl[(ks + 1) * 8192 + c * 512];
      }
      bf16x8 a[8];
#pragma unroll
      for (int r = 0; r < 8; ++r)
        a[r] = *(const bf16x8*)&Hs[(size_t)(r * 16 + lr) * LH + ks * 32 + q * 8];
      __builtin_amdgcn_s_setprio(1);
#pragma unroll
      for (int r = 0; r < 8; ++r)
#pragma unroll
        for (int c = 0; c < 4; ++c)
          acc[r][c] = __builtin_amdgcn_mfma_f32_16x16x32_bf16(a[r], bcur[c], acc[r][c], 0, 0, 0);
      __builtin_amdgcn_s_setprio(0);
    }

#pragma unroll
    for (int c = 0; c < 4; ++c) {
      float cs = 0.f;
#pragma unroll
      for (int r = 0; r < 8; ++r)
#pragma unroll
        for (int reg = 0; reg < 4; ++reg)
          cs += fmaxf(acc[r][c][reg] + bias2[c], 0.f);
      cs += __shfl_xor(cs, 16);
      cs += __shfl_xor(cs, 32);
      if (q == 0) atomicAdd(&s_out[n * 256 + wave * 64 + lr + c * 16], cs);
    }
  }
}

// ---------------- K5: f-network + classifier + log_softmax (4-way ILP dot products) ----------
__global__ void f_net(const float* __restrict__ s, const float* __restrict__ fw1,
                      const float* __restrict__ fb1, const float* __restrict__ fw2,
                      const float* __restrict__ fb2, const float* __restrict__ cw,
                      const float* __restrict__ cb, float* __restrict__ out) {
  int n = blockIdx.x, t = threadIdx.x;
  __shared__ float buf[256], buf2[256], zs[32];
  buf[t] = s[n * 256 + t];
  __syncthreads();
  float a0 = 0.f, a1 = 0.f, a2 = 0.f, a3 = 0.f;
  for (int c = 0; c < 256; c += 4) {
    a0 += buf[c]     * fw1[c * 256 + t];
    a1 += buf[c + 1] * fw1[(c + 1) * 256 + t];
    a2 += buf[c + 2] * fw1[(c + 2) * 256 + t];
    a3 += buf[c + 3] * fw1[(c + 3) * 256 + t];
  }
  float a = fmaxf(fb1[t] + ((a0 + a1) + (a2 + a3)), 0.f);
  buf2[t] = a;
  __syncthreads();
  float y0 = 0.f, y1 = 0.f, y2 = 0.f, y3 = 0.f;
  for (int c = 0; c < 256; c += 4) {
    y0 += buf2[c]     * fw2[c * 256 + t];
    y1 += buf2[c + 1] * fw2[(c + 1) * 256 + t];
    y2 += buf2[c + 2] * fw2[(c + 2) * 256 + t];
    y3 += buf2[c + 3] * fw2[(c + 3) * 256 + t];
  }
  float y = fmaxf(fb2[t] + ((y0 + y1) + (y2 + y3)), 0.f);
  __syncthreads();
  buf[t] = y;
  __syncthreads();
  float z = 0.f;
  if (t < 32) {
    float z0 = 0.f, z1 = 0.f, z2 = 0.f, z3 = 0.f;
    for (int c = 0; c < 256; c += 4) {
      z0 += buf[c]     * cw[c * 32 + t];
      z1 += buf[c + 1] * cw[(c + 1) * 32 + t];
      z2 += buf[c + 2] * cw[(c + 2) * 32 + t];
      z3 += buf[c + 3] * cw[(c + 3) * 32 + t];
    }
    z = cb[t] + ((z0 + z1) + (z2 + z3));
    zs[t] = z;
  }
  __syncthreads();
  if (t < 32) {
    float mx = -1e30f;
    for (int c = 0; c < 32; ++c) mx = fmaxf(mx, zs[c]);
    float se = 0.f;
    for (int c = 0; c < 32; ++c) se += expf(zs[c] - mx);
    out[n * 32 + t] = z - mx - logf(se);
  }
}

extern "C" void kernel_launch(void* const* d_in, const int* in_sizes, int n_in,
                              void* d_out, int out_size, void* d_ws, size_t ws_size,
                              hipStream_t stream) {
  const float* img  = (const float*)d_in[0];
  const float* qst  = (const float*)d_in[1];
  const float* w0   = (const float*)d_in[2];
  const float* w1   = (const float*)d_in[3];
  const float* w2   = (const float*)d_in[4];
  const float* w3   = (const float*)d_in[5];
  const float* bs0  = (const float*)d_in[6];
  const float* bb0  = (const float*)d_in[7];
  const float* bs1  = (const float*)d_in[8];
  const float* bb1  = (const float*)d_in[9];
  const float* bs2  = (const float*)d_in[10];
  const float* bb2  = (const float*)d_in[11];
  const float* bs3  = (const float*)d_in[12];
  const float* bb3  = (const float*)d_in[13];
  const float* gw1  = (const float*)d_in[14];
  const float* gb1  = (const float*)d_in[15];
  const float* gw2  = (const float*)d_in[16];
  const float* gb2  = (const float*)d_in[17];
  const float* gw3  = (const float*)d_in[18];
  const float* gb3  = (const float*)d_in[19];
  const float* gw4  = (const float*)d_in[20];
  const float* gb4  = (const float*)d_in[21];
  const float* fw1  = (const float*)d_in[22];
  const float* fb1  = (const float*)d_in[23];
  const float* fw2  = (const float*)d_in[24];
  const float* fb2  = (const float*)d_in[25];
  const float* cw   = (const float*)d_in[26];
  const float* cb   = (const float*)d_in[27];

  char* ws = (char*)d_ws;
  float* c0 = (float*)(ws + 0);                    // 25,165,824 B NCHW (dead after conv1)
  float* c1 = (float*)(ws + 25165824);             //  6,291,456 B NCHW -> 31,457,280
  __bf16* Wt  = (__bf16*)(ws + 31457280);          //   393,216 B -> 31,850,496
  float*  hqb = (float*)(ws + 31850496);           //    65,536 B -> 31,916,032
  float*  sbuf = (float*)(ws + 31916032);          //    65,536 B -> 31,981,568
  float*  hi  = (float*)(ws + 0);                  // 4,194,304 B (dead-c0, written by chain2)
  float*  hj  = (float*)(ws + 4194304);            // 4,194,304 B (dead-c0)

  k1<<<600, 256, 0, stream>>>(img, w0, bs0, bb0, gw2, gw3, gw4, gw1, gb1, qst,
                              c0, Wt, hqb, sbuf);
  conv1_k<<<256, 256, 0, stream>>>(c0, w1, bs1, bb1, c1);
  chain2_k<<<128, 256, 0, stream>>>(c1, w2, bs2, bb2, w3, bs3, bb3, gw1, hi, hj);
  g_fused<<<2048, 256, 0, stream>>>(hi, hj, hqb, Wt, gb2, gb3, gb4, sbuf);
  f_net<<<64, 256, 0, stream>>>(sbuf, fw1, fb1, fw2, fb2, cw, cb, (float*)d_out);
}